// Round 3
// baseline (383.146 us; speedup 1.0000x reference)
//
#include <hip/hip_runtime.h>
#include <stdint.h>

#define BATCH 256
#define CIN   64
#define LIN   4096
#define PADN  3
#define LPAD  4102            /* 4096 + 2*3 */
#define COUT  128
#define KW    7
#define LPOOL 2048
#define NBUCKET 64
#define NPERCH (256LL * 2048LL)

typedef unsigned long long u64;
typedef __attribute__((ext_vector_type(4)))  int i32x4;
typedef __attribute__((ext_vector_type(16))) int i32x16;

#define ACC_ZERO {0,0,0,0,0,0,0,0,0,0,0,0,0,0,0,0}

// ---------------------------------------------------------------------------
// pack_x: x[b][c][l] fp32 -> sx[b_local][l+3][c] i8 sign (+1/-1/0).
// Pad rows (0..2, 4099..4101) = -1 (sign of pad value -1.0).
// ---------------------------------------------------------------------------
__global__ __launch_bounds__(256) void pack_x_kernel(const float* __restrict__ x,
                                                     char* __restrict__ sx,
                                                     int b_base)
{
    const int t  = threadIdx.x;
    const int lt = blockIdx.x;            // 16 tiles of 256 positions
    const int bl = blockIdx.y;            // local batch index in chunk
    const int b  = b_base + bl;
    const int l  = lt * 256 + t;
    const float* xb = x + (size_t)b * CIN * LIN + l;

    int o[16];
    #pragma unroll
    for (int cw = 0; cw < 16; ++cw) {
        unsigned wv = 0;
        #pragma unroll
        for (int j = 0; j < 4; ++j) {
            float v = xb[(size_t)(cw * 4 + j) * LIN];
            unsigned s = (v > 0.0f) ? 1u : ((v < 0.0f) ? 0xFFu : 0u);
            wv |= s << (8 * j);
        }
        o[cw] = (int)wv;
    }
    i32x4* dst = (i32x4*)(sx + ((size_t)bl * LPAD + (l + PADN)) * 64);
    dst[0] = (i32x4){o[0],  o[1],  o[2],  o[3]};
    dst[1] = (i32x4){o[4],  o[5],  o[6],  o[7]};
    dst[2] = (i32x4){o[8],  o[9],  o[10], o[11]};
    dst[3] = (i32x4){o[12], o[13], o[14], o[15]};

    const i32x4 ff = (i32x4){-1, -1, -1, -1};   // bytes 0xFF = sign(-1)
    if (lt == 0 && t < PADN) {
        i32x4* pd = (i32x4*)(sx + ((size_t)bl * LPAD + t) * 64);
        pd[0] = ff; pd[1] = ff; pd[2] = ff; pd[3] = ff;
    }
    if (lt == 15 && t < PADN) {
        i32x4* pd = (i32x4*)(sx + ((size_t)bl * LPAD + (LIN + PADN) + t) * 64);
        pd[0] = ff; pd[1] = ff; pd[2] = ff; pd[3] = ff;
    }
}

// ---------------------------------------------------------------------------
// pack_w: W[co][c][kk] fp32 -> pwb[kk][co][c] i8 sign. (B-operand layout:
// lane n=co reads 16 contiguous c at k-block offset.)
// ---------------------------------------------------------------------------
__global__ __launch_bounds__(256) void pack_w_kernel(const float* __restrict__ w,
                                                     char* __restrict__ pwb)
{
    int idx = blockIdx.x * 256 + threadIdx.x;     // [0, 7*128*64)
    if (idx >= KW * COUT * CIN) return;
    int kk = idx >> 13;            // / (128*64)
    int co = (idx >> 6) & 127;
    int c  = idx & 63;
    float v = w[((size_t)co * CIN + c) * KW + kk];
    pwb[idx] = (char)((v > 0.0f) ? 1 : ((v < 0.0f) ? -1 : 0));
}

// ---------------------------------------------------------------------------
// Conv core (shared by both passes), mfma_i32_32x32x32_i8:
//   A[m=pos][k=c]  : lane row = q0 + (lane&31) + kk, 16 contiguous c bytes
//   B[k=c][n=cout] : preloaded frags from pwb
//   C/D            : col(lane&31)=cout, row=(reg&3)+8*(reg>>2)+4*(lane>>5)=pos
// Pool pairs = adjacent acc regs (2r, 2r+1): same lane, no shuffles.
// ---------------------------------------------------------------------------

__global__ __launch_bounds__(256, 2) void conv_stats_kernel(
    const char* __restrict__ sx, const char* __restrict__ pwb,
    u64* __restrict__ stats, int b_base)
{
    const int tid  = threadIdx.x;
    const int lane = tid & 63;
    const int w    = tid >> 6;         // wave 0..3
    const int ngrp = w & 1;            // co base = ngrp*64
    const int mgrp = w >> 1;           // position half
    const int col  = lane & 31;
    const int hi   = lane >> 5;
    const int bl   = blockIdx.y;
    const int mchunk = blockIdx.x;     // 0..15 (256 positions each)

    i32x4 bf[KW][2][2];                // [kk][k-block][n-tile]
    #pragma unroll
    for (int kk = 0; kk < KW; ++kk)
        #pragma unroll
        for (int kb = 0; kb < 2; ++kb)
            #pragma unroll
            for (int n = 0; n < 2; ++n)
                bf[kk][kb][n] = *(const i32x4*)(pwb +
                    (size_t)((kk * COUT + ngrp * 64 + n * 32 + col) * 64
                             + kb * 32 + hi * 16));

    const char* sxb = sx + (size_t)bl * LPAD * 64;
    int sp0=0, sn0=0, qp0=0, qn0=0, sp1=0, sn1=0, qp1=0, qn1=0;

    for (int mt = 0; mt < 4; ++mt) {
        const int q0 = mchunk * 256 + mgrp * 128 + mt * 32;
        i32x16 acc0 = ACC_ZERO, acc1 = ACC_ZERO;
        #pragma unroll
        for (int kk = 0; kk < KW; ++kk) {
            const char* ar = sxb + (size_t)(q0 + col + kk) * 64;
            i32x4 a0 = *(const i32x4*)(ar + hi * 16);
            i32x4 a1 = *(const i32x4*)(ar + 32 + hi * 16);
            acc0 = __builtin_amdgcn_mfma_i32_32x32x32_i8(a0, bf[kk][0][0], acc0, 0, 0, 0);
            acc0 = __builtin_amdgcn_mfma_i32_32x32x32_i8(a1, bf[kk][1][0], acc0, 0, 0, 0);
            acc1 = __builtin_amdgcn_mfma_i32_32x32x32_i8(a0, bf[kk][0][1], acc1, 0, 0, 0);
            acc1 = __builtin_amdgcn_mfma_i32_32x32x32_i8(a1, bf[kk][1][1], acc1, 0, 0, 0);
        }
        #pragma unroll
        for (int r = 0; r < 8; ++r) {
            int p = acc0[2*r] > acc0[2*r+1] ? acc0[2*r] : acc0[2*r+1];
            int q = p * p;
            bool pos = p > 0;
            sp0 += pos ? p : 0;  sn0 += pos ? 0 : p;
            qp0 += pos ? q : 0;  qn0 += pos ? 0 : q;
            p = acc1[2*r] > acc1[2*r+1] ? acc1[2*r] : acc1[2*r+1];
            q = p * p;
            pos = p > 0;
            sp1 += pos ? p : 0;  sn1 += pos ? 0 : p;
            qp1 += pos ? q : 0;  qn1 += pos ? 0 : q;
        }
    }

    sp0 += __shfl_xor(sp0, 32);  sn0 += __shfl_xor(sn0, 32);
    qp0 += __shfl_xor(qp0, 32);  qn0 += __shfl_xor(qn0, 32);
    sp1 += __shfl_xor(sp1, 32);  sn1 += __shfl_xor(sn1, 32);
    qp1 += __shfl_xor(qp1, 32);  qn1 += __shfl_xor(qn1, 32);

    if (hi == 0) {
        const int bkt = (b_base + bl) & (NBUCKET - 1);
        u64* s0 = stats + (size_t)(bkt * COUT + ngrp * 64 + col) * 4;
        atomicAdd(&s0[0], (u64)(long long)sp0);
        atomicAdd(&s0[1], (u64)(long long)sn0);
        atomicAdd(&s0[2], (u64)(long long)qp0);
        atomicAdd(&s0[3], (u64)(long long)qn0);
        u64* s1 = stats + (size_t)(bkt * COUT + ngrp * 64 + 32 + col) * 4;
        atomicAdd(&s1[0], (u64)(long long)sp1);
        atomicAdd(&s1[1], (u64)(long long)sn1);
        atomicAdd(&s1[2], (u64)(long long)qp1);
        atomicAdd(&s1[3], (u64)(long long)qn1);
    }
}

// ---------------------------------------------------------------------------
// finalize: sum buckets, exact integer sums -> BN scale/shift (double math).
// ---------------------------------------------------------------------------
__global__ void finalize_kernel(const u64* __restrict__ stats,
                                const float* __restrict__ alpha,
                                const float* __restrict__ gamma,
                                const float* __restrict__ beta,
                                float2* __restrict__ scsh)
{
    int c = threadIdx.x;
    if (c >= COUT) return;
    long long s[4] = {0, 0, 0, 0};
    for (int bk = 0; bk < NBUCKET; ++bk)
        #pragma unroll
        for (int i = 0; i < 4; ++i)
            s[i] += (long long)stats[(size_t)(bk * COUT + c) * 4 + i];
    double a    = (double)alpha[0];
    double N    = (double)NPERCH;
    double sum  = (double)s[0] + a * (double)s[1];
    double ssq  = (double)s[2] + a * a * (double)s[3];
    double mean = sum / N;
    double var  = ssq / N - mean * mean;
    double inv  = 1.0 / sqrt(var + 1e-5);
    double g    = (double)gamma[c];
    scsh[c] = make_float2((float)(g * inv),
                          (float)((double)beta[c] - mean * g * inv));
}

// ---------------------------------------------------------------------------
// Pass B: same MFMA conv, + pool + PReLU + BN affine, fp32 out.
// ---------------------------------------------------------------------------
__global__ __launch_bounds__(256, 2) void conv_write_kernel(
    const char* __restrict__ sx, const char* __restrict__ pwb,
    const float2* __restrict__ scsh, const float* __restrict__ alpha,
    float* __restrict__ out, int b_base)
{
    const int tid  = threadIdx.x;
    const int lane = tid & 63;
    const int w    = tid >> 6;
    const int ngrp = w & 1;
    const int mgrp = w >> 1;
    const int col  = lane & 31;
    const int hi   = lane >> 5;
    const int bl   = blockIdx.y;
    const int mchunk = blockIdx.x;

    i32x4 bf[KW][2][2];
    #pragma unroll
    for (int kk = 0; kk < KW; ++kk)
        #pragma unroll
        for (int kb = 0; kb < 2; ++kb)
            #pragma unroll
            for (int n = 0; n < 2; ++n)
                bf[kk][kb][n] = *(const i32x4*)(pwb +
                    (size_t)((kk * COUT + ngrp * 64 + n * 32 + col) * 64
                             + kb * 32 + hi * 16));

    const char* sxb = sx + (size_t)bl * LPAD * 64;
    const float a = alpha[0];
    const float2 ss0 = scsh[ngrp * 64 + col];
    const float2 ss1 = scsh[ngrp * 64 + 32 + col];
    const int gb = b_base + bl;
    float* orow0 = out + ((size_t)gb * COUT + ngrp * 64 + col) * LPOOL;
    float* orow1 = orow0 + (size_t)32 * LPOOL;

    for (int mt = 0; mt < 4; ++mt) {
        const int q0 = mchunk * 256 + mgrp * 128 + mt * 32;
        i32x16 acc0 = ACC_ZERO, acc1 = ACC_ZERO;
        #pragma unroll
        for (int kk = 0; kk < KW; ++kk) {
            const char* ar = sxb + (size_t)(q0 + col + kk) * 64;
            i32x4 a0 = *(const i32x4*)(ar + hi * 16);
            i32x4 a1 = *(const i32x4*)(ar + 32 + hi * 16);
            acc0 = __builtin_amdgcn_mfma_i32_32x32x32_i8(a0, bf[kk][0][0], acc0, 0, 0, 0);
            acc0 = __builtin_amdgcn_mfma_i32_32x32x32_i8(a1, bf[kk][1][0], acc0, 0, 0, 0);
            acc1 = __builtin_amdgcn_mfma_i32_32x32x32_i8(a0, bf[kk][0][1], acc1, 0, 0, 0);
            acc1 = __builtin_amdgcn_mfma_i32_32x32x32_i8(a1, bf[kk][1][1], acc1, 0, 0, 0);
        }
        const int lp0 = q0 >> 1;
        #pragma unroll
        for (int r = 0; r < 8; ++r) {
            const int prow = (r & 1) + 4 * (r >> 1) + 2 * hi;
            int p = acc0[2*r] > acc0[2*r+1] ? acc0[2*r] : acc0[2*r+1];
            float y = (p > 0) ? (float)p : a * (float)p;
            orow0[lp0 + prow] = fmaf(y, ss0.x, ss0.y);
            p = acc1[2*r] > acc1[2*r+1] ? acc1[2*r] : acc1[2*r+1];
            y = (p > 0) ? (float)p : a * (float)p;
            orow1[lp0 + prow] = fmaf(y, ss1.x, ss1.y);
        }
    }
}

// ---------------------------------------------------------------------------
extern "C" void kernel_launch(void* const* d_in, const int* in_sizes, int n_in,
                              void* d_out, int out_size, void* d_ws, size_t ws_size,
                              hipStream_t stream)
{
    const float* x     = (const float*)d_in[0];
    const float* W     = (const float*)d_in[1];
    const float* alpha = (const float*)d_in[2];
    const float* gamma = (const float*)d_in[3];
    const float* beta  = (const float*)d_in[4];
    float* out = (float*)d_out;

    const size_t PER_B    = (size_t)LPAD * 64;            // 262,528 B / batch
    const size_t pwb_sz   = (size_t)KW * COUT * CIN;      // 57,344
    const size_t stats_sz = (size_t)NBUCKET * COUT * 4 * 8; // 262,144
    const size_t scsh_sz  = (size_t)COUT * 8;
    const size_t fixed    = pwb_sz + stats_sz + scsh_sz + 1024;

    int nb = BATCH;
    if (ws_size < PER_B * BATCH + fixed) {
        size_t avail = (ws_size > fixed) ? (ws_size - fixed) : PER_B;
        nb = (int)(avail / PER_B);
        if (nb < 1) nb = 1;
        if (nb > BATCH) nb = BATCH;
    }

    char* ws = (char*)d_ws;
    char* sx = ws;
    size_t off = ((PER_B * (size_t)nb) + 255) & ~(size_t)255;
    char* pwb = ws + off;               off = (off + pwb_sz + 255) & ~(size_t)255;
    u64* stats = (u64*)(ws + off);      off = (off + stats_sz + 255) & ~(size_t)255;
    float2* scsh = (float2*)(ws + off);

    hipMemsetAsync(stats, 0, stats_sz, stream);
    pack_w_kernel<<<dim3(224), 256, 0, stream>>>(W, pwb);

    for (int b0 = 0; b0 < BATCH; b0 += nb) {
        int n = (BATCH - b0 < nb) ? (BATCH - b0) : nb;
        pack_x_kernel<<<dim3(16, n), 256, 0, stream>>>(x, sx, b0);
        conv_stats_kernel<<<dim3(16, n), 256, 0, stream>>>(sx, pwb, stats, b0);
    }
    finalize_kernel<<<dim3(1), 128, 0, stream>>>(stats, alpha, gamma, beta, scsh);

    if (nb == BATCH) {
        conv_write_kernel<<<dim3(16, BATCH), 256, 0, stream>>>(sx, pwb, scsh, alpha, out, 0);
    } else {
        for (int b0 = 0; b0 < BATCH; b0 += nb) {
            int n = (BATCH - b0 < nb) ? (BATCH - b0) : nb;
            pack_x_kernel<<<dim3(16, n), 256, 0, stream>>>(x, sx, b0);
            conv_write_kernel<<<dim3(16, n), 256, 0, stream>>>(sx, pwb, scsh, alpha, out, b0);
        }
    }
}